// Round 17
// baseline (161.190 us; speedup 1.0000x reference)
//
#include <hip/hip_runtime.h>
#include <math.h>

// ---------------------------------------------------------------------------
// Deep4Net via bf16 MFMA (fp32 accum). R15 configuration (best, 138.9us)
// run as a MEASUREMENT ROUND: conv12/conv3/conv4 are launched TWICE each
// (idempotent pure overwrites; conv5+head stays single -- atomics).
//   c12+c3+c4 = dur_this_round - 138.9
// Rationale: top-5 profile rows are harness fills (42us), so every kernel of
// ours is individually invisible; 16 rounds of single-variable A/B moved
// 1-5us each while ~90us remains unattributed. This round localizes it.
// Session ledger (dead): coop grid.sync (R6); per-WG cost (R10 confounded,
// R16 clean: VB=2 regressed +8.9); boundaries ~1us (R11); staging format
// (R12); shuffle-pool (R14); VB grid-stride (R16).
//
// Kernel bodies are R15 verbatim (A-hoist TK<=20, two-phase hoist conv5,
// folded head). Weights FRAGMENT-ORDERED; B staged in LDS (padded rows);
// sc transposed odd stride; pool(elu)=elu(pool).
//
// Workspace: float region then short(bf16) region.
#define F_BC   0         // 32   combined bias (padded)
#define F_B2   32        // 64
#define F_B3   96        // 128
#define F_B4   224       // 224
#define SHORT_BASE 717696  // short index of bf16 region
#define WK12   0         // [10][1][2][512]   (k, ib, otile, frag)
#define WK3    10240     // [10][1][4][512]
#define WK4    30720     // [10][2][8][512]
#define WK5    112640    // [10][4][14][512]
#define P1T    399360    // [256][330][32]
#define P2T    3102720   // [256][107][64]
#define P3T    4855808   // [256][32][128]
#define P0T    5904384   // [256][1000][32]  pre-transposed bf16 input
// ---------------------------------------------------------------------------

typedef __attribute__((ext_vector_type(8))) short short8;
typedef __attribute__((ext_vector_type(4))) float f32x4;

__device__ __forceinline__ short f2bf(float f) {
    union { float f; unsigned u; } v; v.f = f;
    unsigned r = v.u + 0x7FFF + ((v.u >> 16) & 1);
    return (short)(r >> 16);
}

// ---- K0: weight prep + coalesced x transpose ------------------------------
__global__ __launch_bounds__(256) void k_prep2(
    const float* __restrict__ x,
    const float* __restrict__ wt, const float* __restrict__ bt,
    const float* __restrict__ wsp, const float* __restrict__ bsp,
    const float* __restrict__ w2, const float* __restrict__ b2,
    const float* __restrict__ w3, const float* __restrict__ b3,
    const float* __restrict__ w4, const float* __restrict__ b4,
    float* __restrict__ wsf, short* __restrict__ wss) {
    int tid = threadIdx.x;
    if (blockIdx.x == 0) {
        __shared__ float bacc[32];
        if (tid < 32) bacc[tid] = 0.f;
        __syncthreads();
        for (int p = tid; p < 625; p += 256) {      // combined bias reduction
            int o = p / 25, i = p - o * 25;
            float rs = 0.f;
            for (int c = 0; c < 22; ++c) rs += wsp[(o * 25 + i) * 22 + c];
            atomicAdd(&bacc[o], bt[i] * rs);
        }
        __syncthreads();
        for (int idx = tid; idx < 448; idx += 256) {
            float v;
            if (idx < 32)        v = (idx < 25) ? bsp[idx] + bacc[idx] : 0.f;
            else if (idx < 96)  { int o = idx - 32;  v = (o < 50)  ? b2[o] : 0.f; }
            else if (idx < 224) { int o = idx - 96;  v = (o < 100) ? b3[o] : 0.f; }
            else                { int o = idx - 224; v = (o < 200) ? b4[o] : 0.f; }
            wsf[idx] = v;
        }
        return;
    }
    if (blockIdx.x >= 1561) {                  // x transpose, coalesced writes
        int bidx = blockIdx.x - 1561;          // 256 samples x 16 t-chunks
        int b = bidx >> 4, tc = bidx & 15;
        int t = tc * 64 + (tid >> 2);          // 64 t per block
        if (t < 1000) {
            int co = (tid & 3) * 8;            // channel octet 0/8/16/24
            const float* xb = x + (size_t)b * 22000;
            short8 v;
#pragma unroll
            for (int j = 0; j < 8; ++j) {
                int c = co + j;
                v[j] = (c < 22) ? f2bf(xb[c * 1000 + t]) : (short)0;
            }
            *(short8*)(wss + P0T + (size_t)b * 32000 + t * 32 + co) = v;
        }
        return;
    }
    int j = (blockIdx.x - 1) * 256 + tid;
    if (j < 10240) {                           // wk12 combined: OPAD=32, IB=1
        int g = j >> 9, s = j & 511;
        int k = g >> 1, ot = g & 1;
        int lane = s >> 3, e = s & 7;
        int o = ot * 16 + (lane & 15), i = (lane >> 4) * 8 + e;
        float v = 0.f;
        if (o < 25 && i < 22)
            for (int q = 0; q < 25; ++q) v += wt[q * 10 + k] * wsp[(o * 25 + q) * 22 + i];
        wss[WK12 + j] = f2bf(v);
        return;
    }
    j -= 10240;
    if (j < 20480) {                           // wk3: OPAD=64, IB=1 (4 blk/k)
        int g = j >> 9, s = j & 511;
        int k = g >> 2, ot = g & 3;
        int lane = s >> 3, e = s & 7;
        int o = ot * 16 + (lane & 15), i = (lane >> 4) * 8 + e;
        float v = (o < 50 && i < 25) ? w2[(o * 25 + i) * 10 + k] : 0.f;
        wss[WK3 + j] = f2bf(v);
        return;
    }
    j -= 20480;
    if (j < 81920) {                           // wk4: OPAD=128, IB=2 (16 blk/k)
        int g = j >> 9, s = j & 511;
        int k = g >> 4, rem = g & 15, ib = rem >> 3, ot = rem & 7;
        int lane = s >> 3, e = s & 7;
        int o = ot * 16 + (lane & 15), i = ib * 32 + (lane >> 4) * 8 + e;
        float v = (o < 100 && i < 50) ? w3[(o * 50 + i) * 10 + k] : 0.f;
        wss[WK4 + j] = f2bf(v);
        return;
    }
    j -= 81920;
    if (j < 286720) {                          // wk5: OPAD=224, IB=4 (56 blk/k)
        int g = j >> 9, s = j & 511;
        int k = g / 56, rem = g % 56, ib = rem / 14, ot = rem % 14;
        int lane = s >> 3, e = s & 7;
        int o = ot * 16 + (lane & 15), i = ib * 32 + (lane >> 4) * 8 + e;
        float v = (o < 200 && i < 100) ? w4[(o * 100 + i) * 10 + k] : 0.f;
        wss[WK5 + j] = f2bf(v);
    }
}

// ---- generic MFMA conv+pool+ELU layer (R15 verbatim) ----------------------
template<int OPAD, int IPAD, int IB, int WM, int NT, int NCHUNK, bool LAST>
__global__ __launch_bounds__(256) void k_cmfma(
    const short* __restrict__ wk, const float* __restrict__ bias,
    const short* __restrict__ xinT,
    short* __restrict__ outT,
    const float* __restrict__ hW, const float* __restrict__ hB,
    const int* __restrict__ sid, float* __restrict__ out,
    int NC, int TIN, int NPtot) {
    constexpr int ROWS = NCHUNK + 9;
    constexpr int MSPAN = WM * 16;
    constexpr int XSTR = IPAD + 4;      // +4 shorts: bank-conflict-free rows
    constexpr int SSTR = MSPAN + 1;     // odd stride: conflict-free sc
    __shared__ short xs[ROWS * XSTR];
    __shared__ float sc[NCHUNK * SSTR];
    __shared__ float feats[LAST ? MSPAN * 7 : 1];

    int idx = blockIdx.x;
    int b = idx % 256;
    int nc = (idx / 256) % NC;
    int mc = idx / (256 * NC);
    int t0 = nc * NCHUNK;
    int tid = threadIdx.x;

    // ---- stage input tile into LDS (bf16, time-major, vector loads) ----
    {
        const short* xb = xinT + (size_t)b * TIN * IPAD;
        constexpr int V = IPAD / 8;
        for (int i = tid; i < ROWS * V; i += 256) {
            int r = i / V, vv = i - r * V;
            int t = t0 + r; if (t >= TIN) t = TIN - 1;   // clamp; extras discarded
            *(short8*)(xs + r * XSTR + vv * 8) =
                *(const short8*)(xb + (size_t)t * IPAD + vv * 8);
        }
    }
    __syncthreads();

    int w = tid >> 6, lane = tid & 63, l15 = lane & 15, quad = lane >> 4;
    int mt = w % WM, ns = w / WM;
    int otg = mc * WM + mt;             // global otile index for A blocks
    int tw = ns * NT * 16;

    f32x4 acc[NT];
#pragma unroll
    for (int i = 0; i < NT; ++i) acc[i] = (f32x4){0.f, 0.f, 0.f, 0.f};

    const short* wfrag = wk + lane * 8; // lane's 16B within each 512-short block
    constexpr int TK = 10 * IB;
    if constexpr (TK <= 20) {
        // ---- single A-hoist: all fragments to registers, unrolled k-loop ----
        short8 afr[TK];
#pragma unroll
        for (int t = 0; t < TK; ++t)
            afr[t] = *(const short8*)(wfrag + (size_t)(t * (OPAD / 16) + otg) * 512);
#pragma unroll
        for (int k = 0; k < 10; ++k)
#pragma unroll
            for (int ib = 0; ib < IB; ++ib)
#pragma unroll
                for (int nt = 0; nt < NT; ++nt) {
                    short8 bf = *(const short8*)(xs + (tw + nt * 16 + l15 + k) * XSTR +
                                                 ib * 32 + quad * 8);
                    acc[nt] = __builtin_amdgcn_mfma_f32_16x16x32_bf16(
                        afr[k * IB + ib], bf, acc[nt], 0, 0, 0);
                }
    } else {
        // ---- two-phase A-hoist (TK=40, conv5): 20 frags per phase ----
        short8 afr[20];
#pragma unroll
        for (int h = 0; h < 2; ++h) {
#pragma unroll
            for (int t = 0; t < 20; ++t)
                afr[t] = *(const short8*)(wfrag +
                    (size_t)((h * 20 + t) * (OPAD / 16) + otg) * 512);
#pragma unroll
            for (int k = 0; k < 5; ++k)
#pragma unroll
                for (int ib = 0; ib < IB; ++ib)
#pragma unroll
                    for (int nt = 0; nt < NT; ++nt) {
                        short8 bf = *(const short8*)(xs +
                            (tw + nt * 16 + l15 + h * 5 + k) * XSTR +
                            ib * 32 + quad * 8);
                        acc[nt] = __builtin_amdgcn_mfma_f32_16x16x32_bf16(
                            afr[k * IB + ib], bf, acc[nt], 0, 0, 0);
                    }
        }
    }

    // ---- C frags -> LDS f32 scratch, transposed: sc[col][o_local] ----
#pragma unroll
    for (int nt = 0; nt < NT; ++nt) {
        int col = tw + nt * 16 + l15;
        int rbase = mt * 16 + quad * 4;
#pragma unroll
        for (int r = 0; r < 4; ++r)
            sc[col * SSTR + rbase + r] = acc[nt][r];
    }
    __syncthreads();

    // ---- pool3 + bias + ELU + store (bf16 transposed, or LDS feats) ----
    constexpr int PC = NCHUNK / 3;
    int pc0 = nc * PC;
    for (int i = tid; i < PC * MSPAN; i += 256) {
        int tp = i / MSPAN, ol = i - tp * MSPAN;
        if (pc0 + tp < NPtot) {
            float s0 = sc[(tp * 3 + 0) * SSTR + ol];
            float s1 = sc[(tp * 3 + 1) * SSTR + ol];
            float s2 = sc[(tp * 3 + 2) * SSTR + ol];
            float m = fmaxf(fmaxf(s0, s1), s2) + bias[mc * MSPAN + ol];
            float e = m > 0.f ? m : __expf(m) - 1.f;
            if constexpr (LAST) {
                feats[ol * 7 + (pc0 + tp)] = e;
            } else {
                outT[(size_t)b * NPtot * OPAD + (size_t)(pc0 + tp) * OPAD +
                     mc * MSPAN + ol] = f2bf(e);
            }
        }
    }

    if constexpr (LAST) {
        // ---- folded head: wave w -> output w; this block's feats slice ----
        __syncthreads();
        int nvo = 200 - mc * MSPAN; if (nvo > MSPAN) nvo = MSPAN;
        int nvalid = nvo * 7;                    // 224, or 56 at mc==6
        int s = sid[b];
        const float* wrow = hW + (size_t)(s * 4 + w) * 1400 + mc * MSPAN * 7;
        float hacc = 0.f;
        for (int f = lane; f < nvalid; f += 64) hacc += wrow[f] * feats[f];
#pragma unroll
        for (int off = 32; off; off >>= 1) hacc += __shfl_down(hacc, off);
        if (lane == 0) {
            if (mc == 0) hacc += hB[s * 4 + w];
            atomicAdd(&out[b * 4 + w], hacc);   // out memset-0 by harness
        }
    }
}

extern "C" void kernel_launch(void* const* d_in, const int* in_sizes, int n_in,
                              void* d_out, int out_size, void* d_ws, size_t ws_size,
                              hipStream_t stream) {
    const float* x   = (const float*)d_in[0];
    const int*   sid = (const int*)d_in[1];
    const float* wt  = (const float*)d_in[2];
    const float* bt  = (const float*)d_in[3];
    const float* wsp = (const float*)d_in[4];
    const float* bsp = (const float*)d_in[5];
    const float* w2  = (const float*)d_in[6];
    const float* b2  = (const float*)d_in[7];
    const float* w3  = (const float*)d_in[8];
    const float* b3  = (const float*)d_in[9];
    const float* w4  = (const float*)d_in[10];
    const float* b4  = (const float*)d_in[11];
    const float* hW  = (const float*)d_in[12];
    const float* hB  = (const float*)d_in[13];
    float* out = (float*)d_out;
    float* wsf = (float*)d_ws;
    short* wss = (short*)d_ws + SHORT_BASE;

    // prep: blk 0 = biases; 1..1560 = weights; 1561..5656 = x transpose
    k_prep2<<<5657, 256, 0, stream>>>(x, wt, bt, wsp, bsp, w2, b2, w3, b3,
                                      w4, b4, wsf, wss);
    // MEASUREMENT: conv12/conv3/conv4 launched twice (idempotent overwrites).
    // c12+c3+c4 = dur(this round) - 138.9us (R15 baseline).
    k_cmfma<32, 32, 1, 2, 3, 96, false><<<256 * 11, 256, 0, stream>>>(
        wss + WK12, wsf + F_BC, wss + P0T, wss + P1T,
        nullptr, nullptr, nullptr, nullptr, 11, 1000, 330);
    k_cmfma<32, 32, 1, 2, 3, 96, false><<<256 * 11, 256, 0, stream>>>(
        wss + WK12, wsf + F_BC, wss + P0T, wss + P1T,
        nullptr, nullptr, nullptr, nullptr, 11, 1000, 330);
    k_cmfma<64, 32, 1, 4, 3, 48, false><<<256 * 7, 256, 0, stream>>>(
        wss + WK3, wsf + F_B2, wss + P1T, wss + P2T,
        nullptr, nullptr, nullptr, nullptr, 7, 330, 107);
    k_cmfma<64, 32, 1, 4, 3, 48, false><<<256 * 7, 256, 0, stream>>>(
        wss + WK3, wsf + F_B2, wss + P1T, wss + P2T,
        nullptr, nullptr, nullptr, nullptr, 7, 330, 107);
    k_cmfma<128, 64, 2, 4, 3, 48, false><<<256 * 2 * 2, 256, 0, stream>>>(
        wss + WK4, wsf + F_B3, wss + P2T, wss + P3T,
        nullptr, nullptr, nullptr, nullptr, 2, 107, 32);
    k_cmfma<128, 64, 2, 4, 3, 48, false><<<256 * 2 * 2, 256, 0, stream>>>(
        wss + WK4, wsf + F_B3, wss + P2T, wss + P3T,
        nullptr, nullptr, nullptr, nullptr, 2, 107, 32);
    // conv5+head: single (head atomicAdd not idempotent)
    k_cmfma<224, 128, 4, 2, 1, 32, true><<<256 * 7, 256, 0, stream>>>(
        wss + WK5, wsf + F_B4, wss + P3T, nullptr,
        hW, hB, sid, out, 1, 32, 7);
}

// Round 18
// 136.461 us; speedup vs baseline: 1.1812x; 1.1812x over previous
//
#include <hip/hip_runtime.h>
#include <math.h>

// ---------------------------------------------------------------------------
// Deep4Net via bf16 MFMA (fp32 accum). R15 base (best, 138.9us) + conv5
// rebuilt WM=4/NT=2.
// Session ledger (dead): coop grid.sync (R6); per-WG cost (R10/R16); launch
// boundaries ~1us (R11); staging format (R12); shuffle-pool (R14); VB
// grid-stride (R16). MEASURED (R17): c12+c3+c4 ~= 20us; with prep ~15
// (R4/R11/R12 arithmetic) and fill 42.5 harness-fixed, conv5 ~= 45-55us.
// Mechanism: WM=2/NT=1 duplicated A-fragments across wave pairs -> 287MB of
// L2 A-traffic (at the L2 ceiling) + a single 40-deep dependent MFMA chain.
// R18: conv5 WM=4/NT=2 -> zero A-duplication (164MB), 2 independent acc
// chains, grid 1792->1024 (4 blocks/CU). Per-output k-major accumulation
// order unchanged -> conv outputs bit-identical; head partials regroup 7->4
// slices (fp32 ~1e-6, threshold 0.035).
//
// conv1+conv2 fused algebraically; pool(elu)=elu(pool).
//   out[o][t] += sum_i wk[k][o][i] * xT[t+k][i]
// Weights FRAGMENT-ORDERED by prep: for each (k, ib, otile) a 512-short
// block where lane l holds shorts [l*8..+7] = its exact MFMA A-fragment ->
// wave A-load = one coalesced 1KB global_load_dwordx4 (A-hoisted, R13/R15).
// B-frag: xT[t][i: quad*8..+7] staged in LDS (rows padded +4 shorts).
// Epilogue scratch sc transposed [col][o], odd stride MSPAN+1.
// LAST: feats in typed LDS + folded head (atomicAdd into harness-zeroed out).
//
// Workspace: float region then short(bf16) region.
#define F_BC   0         // 32   combined bias (padded)
#define F_B2   32        // 64
#define F_B3   96        // 128
#define F_B4   224       // 224
#define SHORT_BASE 717696  // short index of bf16 region
#define WK12   0         // [10][1][2][512]   (k, ib, otile, frag)
#define WK3    10240     // [10][1][4][512]
#define WK4    30720     // [10][2][8][512]
#define WK5    112640    // [10][4][14][512]
#define P1T    399360    // [256][330][32]
#define P2T    3102720   // [256][107][64]
#define P3T    4855808   // [256][32][128]
#define P0T    5904384   // [256][1000][32]  pre-transposed bf16 input
// ---------------------------------------------------------------------------

typedef __attribute__((ext_vector_type(8))) short short8;
typedef __attribute__((ext_vector_type(4))) float f32x4;

__device__ __forceinline__ short f2bf(float f) {
    union { float f; unsigned u; } v; v.f = f;
    unsigned r = v.u + 0x7FFF + ((v.u >> 16) & 1);
    return (short)(r >> 16);
}

// ---- K0: weight prep + coalesced x transpose ------------------------------
__global__ __launch_bounds__(256) void k_prep2(
    const float* __restrict__ x,
    const float* __restrict__ wt, const float* __restrict__ bt,
    const float* __restrict__ wsp, const float* __restrict__ bsp,
    const float* __restrict__ w2, const float* __restrict__ b2,
    const float* __restrict__ w3, const float* __restrict__ b3,
    const float* __restrict__ w4, const float* __restrict__ b4,
    float* __restrict__ wsf, short* __restrict__ wss) {
    int tid = threadIdx.x;
    if (blockIdx.x == 0) {
        __shared__ float bacc[32];
        if (tid < 32) bacc[tid] = 0.f;
        __syncthreads();
        for (int p = tid; p < 625; p += 256) {      // combined bias reduction
            int o = p / 25, i = p - o * 25;
            float rs = 0.f;
            for (int c = 0; c < 22; ++c) rs += wsp[(o * 25 + i) * 22 + c];
            atomicAdd(&bacc[o], bt[i] * rs);
        }
        __syncthreads();
        for (int idx = tid; idx < 448; idx += 256) {
            float v;
            if (idx < 32)        v = (idx < 25) ? bsp[idx] + bacc[idx] : 0.f;
            else if (idx < 96)  { int o = idx - 32;  v = (o < 50)  ? b2[o] : 0.f; }
            else if (idx < 224) { int o = idx - 96;  v = (o < 100) ? b3[o] : 0.f; }
            else                { int o = idx - 224; v = (o < 200) ? b4[o] : 0.f; }
            wsf[idx] = v;
        }
        return;
    }
    if (blockIdx.x >= 1561) {                  // x transpose, coalesced writes
        int bidx = blockIdx.x - 1561;          // 256 samples x 16 t-chunks
        int b = bidx >> 4, tc = bidx & 15;
        int t = tc * 64 + (tid >> 2);          // 64 t per block
        if (t < 1000) {
            int co = (tid & 3) * 8;            // channel octet 0/8/16/24
            const float* xb = x + (size_t)b * 22000;
            short8 v;
#pragma unroll
            for (int j = 0; j < 8; ++j) {
                int c = co + j;
                v[j] = (c < 22) ? f2bf(xb[c * 1000 + t]) : (short)0;
            }
            *(short8*)(wss + P0T + (size_t)b * 32000 + t * 32 + co) = v;
        }
        return;
    }
    int j = (blockIdx.x - 1) * 256 + tid;
    if (j < 10240) {                           // wk12 combined: OPAD=32, IB=1
        int g = j >> 9, s = j & 511;
        int k = g >> 1, ot = g & 1;
        int lane = s >> 3, e = s & 7;
        int o = ot * 16 + (lane & 15), i = (lane >> 4) * 8 + e;
        float v = 0.f;
        if (o < 25 && i < 22)
            for (int q = 0; q < 25; ++q) v += wt[q * 10 + k] * wsp[(o * 25 + q) * 22 + i];
        wss[WK12 + j] = f2bf(v);
        return;
    }
    j -= 10240;
    if (j < 20480) {                           // wk3: OPAD=64, IB=1 (4 blk/k)
        int g = j >> 9, s = j & 511;
        int k = g >> 2, ot = g & 3;
        int lane = s >> 3, e = s & 7;
        int o = ot * 16 + (lane & 15), i = (lane >> 4) * 8 + e;
        float v = (o < 50 && i < 25) ? w2[(o * 25 + i) * 10 + k] : 0.f;
        wss[WK3 + j] = f2bf(v);
        return;
    }
    j -= 20480;
    if (j < 81920) {                           // wk4: OPAD=128, IB=2 (16 blk/k)
        int g = j >> 9, s = j & 511;
        int k = g >> 4, rem = g & 15, ib = rem >> 3, ot = rem & 7;
        int lane = s >> 3, e = s & 7;
        int o = ot * 16 + (lane & 15), i = ib * 32 + (lane >> 4) * 8 + e;
        float v = (o < 100 && i < 50) ? w3[(o * 50 + i) * 10 + k] : 0.f;
        wss[WK4 + j] = f2bf(v);
        return;
    }
    j -= 81920;
    if (j < 286720) {                          // wk5: OPAD=224, IB=4 (56 blk/k)
        int g = j >> 9, s = j & 511;
        int k = g / 56, rem = g % 56, ib = rem / 14, ot = rem % 14;
        int lane = s >> 3, e = s & 7;
        int o = ot * 16 + (lane & 15), i = ib * 32 + (lane >> 4) * 8 + e;
        float v = (o < 200 && i < 100) ? w4[(o * 100 + i) * 10 + k] : 0.f;
        wss[WK5 + j] = f2bf(v);
    }
}

// ---- generic MFMA conv+pool+ELU layer -------------------------------------
// block = 4 waves: wave w -> (m-tile w%WM, n-group w/WM of NT 16-wide tiles)
// grid: idx = b + 256*(nc + NC*mc). Typed separate xs/sc.
// A-HOIST: TK<=20 single hoist (R13); TK==40 two-phase (R15).
// LAST: typed feats LDS + folded head (atomicAdd into harness-zeroed out).
template<int OPAD, int IPAD, int IB, int WM, int NT, int NCHUNK, bool LAST>
__global__ __launch_bounds__(256) void k_cmfma(
    const short* __restrict__ wk, const float* __restrict__ bias,
    const short* __restrict__ xinT,
    short* __restrict__ outT,
    const float* __restrict__ hW, const float* __restrict__ hB,
    const int* __restrict__ sid, float* __restrict__ out,
    int NC, int TIN, int NPtot) {
    constexpr int ROWS = NCHUNK + 9;
    constexpr int MSPAN = WM * 16;
    constexpr int XSTR = IPAD + 4;      // +4 shorts: bank-conflict-free rows
    constexpr int SSTR = MSPAN + 1;     // odd stride: conflict-free sc
    __shared__ short xs[ROWS * XSTR];
    __shared__ float sc[NCHUNK * SSTR];
    __shared__ float feats[LAST ? MSPAN * 7 : 1];

    int idx = blockIdx.x;
    int b = idx % 256;
    int nc = (idx / 256) % NC;
    int mc = idx / (256 * NC);
    int t0 = nc * NCHUNK;
    int tid = threadIdx.x;

    // ---- stage input tile into LDS (bf16, time-major, vector loads) ----
    {
        const short* xb = xinT + (size_t)b * TIN * IPAD;
        constexpr int V = IPAD / 8;
        for (int i = tid; i < ROWS * V; i += 256) {
            int r = i / V, vv = i - r * V;
            int t = t0 + r; if (t >= TIN) t = TIN - 1;   // clamp; extras discarded
            *(short8*)(xs + r * XSTR + vv * 8) =
                *(const short8*)(xb + (size_t)t * IPAD + vv * 8);
        }
    }
    __syncthreads();

    int w = tid >> 6, lane = tid & 63, l15 = lane & 15, quad = lane >> 4;
    int mt = w % WM, ns = w / WM;
    int otg = mc * WM + mt;             // global otile index for A blocks
    int tw = ns * NT * 16;

    f32x4 acc[NT];
#pragma unroll
    for (int i = 0; i < NT; ++i) acc[i] = (f32x4){0.f, 0.f, 0.f, 0.f};

    const short* wfrag = wk + lane * 8; // lane's 16B within each 512-short block
    constexpr int TK = 10 * IB;
    if constexpr (TK <= 20) {
        // ---- single A-hoist: all fragments to registers, unrolled k-loop ----
        short8 afr[TK];
#pragma unroll
        for (int t = 0; t < TK; ++t)
            afr[t] = *(const short8*)(wfrag + (size_t)(t * (OPAD / 16) + otg) * 512);
#pragma unroll
        for (int k = 0; k < 10; ++k)
#pragma unroll
            for (int ib = 0; ib < IB; ++ib)
#pragma unroll
                for (int nt = 0; nt < NT; ++nt) {
                    short8 bf = *(const short8*)(xs + (tw + nt * 16 + l15 + k) * XSTR +
                                                 ib * 32 + quad * 8);
                    acc[nt] = __builtin_amdgcn_mfma_f32_16x16x32_bf16(
                        afr[k * IB + ib], bf, acc[nt], 0, 0, 0);
                }
    } else {
        // ---- two-phase A-hoist (TK=40, conv5): 20 frags per phase ----
        short8 afr[20];
#pragma unroll
        for (int h = 0; h < 2; ++h) {
#pragma unroll
            for (int t = 0; t < 20; ++t)
                afr[t] = *(const short8*)(wfrag +
                    (size_t)((h * 20 + t) * (OPAD / 16) + otg) * 512);
#pragma unroll
            for (int k = 0; k < 5; ++k)
#pragma unroll
                for (int ib = 0; ib < IB; ++ib)
#pragma unroll
                    for (int nt = 0; nt < NT; ++nt) {
                        short8 bf = *(const short8*)(xs +
                            (tw + nt * 16 + l15 + h * 5 + k) * XSTR +
                            ib * 32 + quad * 8);
                        acc[nt] = __builtin_amdgcn_mfma_f32_16x16x32_bf16(
                            afr[k * IB + ib], bf, acc[nt], 0, 0, 0);
                    }
        }
    }

    // ---- C frags -> LDS f32 scratch, transposed: sc[col][o_local] ----
#pragma unroll
    for (int nt = 0; nt < NT; ++nt) {
        int col = tw + nt * 16 + l15;
        int rbase = mt * 16 + quad * 4;
#pragma unroll
        for (int r = 0; r < 4; ++r)
            sc[col * SSTR + rbase + r] = acc[nt][r];
    }
    __syncthreads();

    // ---- pool3 + bias + ELU + store (bf16 transposed, or LDS feats) ----
    constexpr int PC = NCHUNK / 3;
    int pc0 = nc * PC;
    for (int i = tid; i < PC * MSPAN; i += 256) {
        int tp = i / MSPAN, ol = i - tp * MSPAN;
        if (pc0 + tp < NPtot) {
            float s0 = sc[(tp * 3 + 0) * SSTR + ol];
            float s1 = sc[(tp * 3 + 1) * SSTR + ol];
            float s2 = sc[(tp * 3 + 2) * SSTR + ol];
            float m = fmaxf(fmaxf(s0, s1), s2) + bias[mc * MSPAN + ol];
            float e = m > 0.f ? m : __expf(m) - 1.f;
            if constexpr (LAST) {
                feats[ol * 7 + (pc0 + tp)] = e;
            } else {
                outT[(size_t)b * NPtot * OPAD + (size_t)(pc0 + tp) * OPAD +
                     mc * MSPAN + ol] = f2bf(e);
            }
        }
    }

    if constexpr (LAST) {
        // ---- folded head: wave w -> output w; this block's feats slice ----
        __syncthreads();
        int nvo = 200 - mc * MSPAN; if (nvo > MSPAN) nvo = MSPAN;
        int nvalid = nvo * 7;                    // 448, or 56 at last mc
        int s = sid[b];
        const float* wrow = hW + (size_t)(s * 4 + w) * 1400 + mc * MSPAN * 7;
        float hacc = 0.f;
        for (int f = lane; f < nvalid; f += 64) hacc += wrow[f] * feats[f];
#pragma unroll
        for (int off = 32; off; off >>= 1) hacc += __shfl_down(hacc, off);
        if (lane == 0) {
            if (mc == 0) hacc += hB[s * 4 + w];
            atomicAdd(&out[b * 4 + w], hacc);   // out memset-0 by harness
        }
    }
}

extern "C" void kernel_launch(void* const* d_in, const int* in_sizes, int n_in,
                              void* d_out, int out_size, void* d_ws, size_t ws_size,
                              hipStream_t stream) {
    const float* x   = (const float*)d_in[0];
    const int*   sid = (const int*)d_in[1];
    const float* wt  = (const float*)d_in[2];
    const float* bt  = (const float*)d_in[3];
    const float* wsp = (const float*)d_in[4];
    const float* bsp = (const float*)d_in[5];
    const float* w2  = (const float*)d_in[6];
    const float* b2  = (const float*)d_in[7];
    const float* w3  = (const float*)d_in[8];
    const float* b3  = (const float*)d_in[9];
    const float* w4  = (const float*)d_in[10];
    const float* b4  = (const float*)d_in[11];
    const float* hW  = (const float*)d_in[12];
    const float* hB  = (const float*)d_in[13];
    float* out = (float*)d_out;
    float* wsf = (float*)d_ws;
    short* wss = (short*)d_ws + SHORT_BASE;

    // prep: blk 0 = biases; 1..1560 = weights; 1561..5656 = x transpose
    k_prep2<<<5657, 256, 0, stream>>>(x, wt, bt, wsp, bsp, w2, b2, w3, b3,
                                      w4, b4, wsf, wss);
    // conv12: M=32(25), 330 pooled; 11 n-chunks of 96 (grid 2816, A-hoist 10)
    k_cmfma<32, 32, 1, 2, 3, 96, false><<<256 * 11, 256, 0, stream>>>(
        wss + WK12, wsf + F_BC, wss + P0T, wss + P1T,
        nullptr, nullptr, nullptr, nullptr, 11, 1000, 330);
    // conv3: M=64(50), 107 pooled; 7 n-chunks of 48 (grid 1792, A-hoist 10)
    k_cmfma<64, 32, 1, 4, 3, 48, false><<<256 * 7, 256, 0, stream>>>(
        wss + WK3, wsf + F_B2, wss + P1T, wss + P2T,
        nullptr, nullptr, nullptr, nullptr, 7, 330, 107);
    // conv4: M=128(100) in 2 m-chunks, 32 pooled; 2 n-chunks (A-hoist 20)
    k_cmfma<128, 64, 2, 4, 3, 48, false><<<256 * 2 * 2, 256, 0, stream>>>(
        wss + WK4, wsf + F_B3, wss + P2T, wss + P3T,
        nullptr, nullptr, nullptr, nullptr, 2, 107, 32);
    // conv5+head: M=224(200), WM=4/NT=2 -> 4 m-chunks, grid 1024 (4 blk/CU),
    // zero A-duplication (164MB L2 traffic, was 287), 2 indep acc chains.
    k_cmfma<224, 128, 4, 4, 2, 32, true><<<256 * 4, 256, 0, stream>>>(
        wss + WK5, wsf + F_B4, wss + P3T, nullptr,
        hW, hB, sid, out, 1, 32, 7);
}